// Round 8
// baseline (98.722 us; speedup 1.0000x reference)
//
#include <hip/hip_runtime.h>
#include <hip/hip_bf16.h>

#define BB 2
#define NN 4096
#define DD 1024
#define HH 16
#define RR 4
#define MM 8
#define CC 64
#define DH 64
#define CG 4          // buckets per k_attn block
#define PAD 68

typedef __attribute__((ext_vector_type(8))) short bf16x8;
typedef __attribute__((ext_vector_type(4))) float f32x4;
typedef unsigned long long u64;

__device__ __forceinline__ unsigned short f2bf(float x) {  // RNE via HW cvt
  union { __hip_bfloat16 b; unsigned short u; } cv;
  cv.b = __float2bfloat16(x);
  return cv.u;
}
// swizzled byte address in a [64 rows][128 bytes] LDS tile (conflict-free b128)
__device__ __forceinline__ int swz(int row, int colbyte) {
  return row * 128 + (colbyte ^ ((row & 7) << 4));
}
__device__ __forceinline__ bf16x8 pack8(float4 a, float4 b, float sc) {
  bf16x8 r;
  const float* pa = (const float*)&a;
  const float* pb = (const float*)&b;
#pragma unroll
  for (int j = 0; j < 4; ++j) {
    r[j] = (short)f2bf(pa[j] * sc);
    r[j + 4] = (short)f2bf(pb[j] * sc);
  }
  return r;
}
// async global->LDS, 16B per lane; LDS dest = base + lane*16 (wave-uniform base)
__device__ __forceinline__ void load_lds16(const void* g, void* l) {
  __builtin_amdgcn_global_load_lds(
      (const __attribute__((address_space(1))) unsigned*)g,
      (__attribute__((address_space(3))) unsigned*)l, 16, 0, 0);
}

// ---------------------------------------------------------------------------
// Kernel 1: LSH hash codes (f32 exact -> bucketing identical to reference)
// ---------------------------------------------------------------------------
__global__ __launch_bounds__(256) void k_hash(const float* __restrict__ q,
                                              const float* __restrict__ proj,
                                              int* __restrict__ codes) {
  int blk = blockIdx.x;
  int nc = blk & (CC - 1);
  int h = (blk >> 6) & (HH - 1);
  int b = blk >> 10;
  __shared__ float Qs[64][PAD];
  __shared__ float Ps[DH][MM];
  __shared__ float Ss[64][9];
  int tid = threadIdx.x;
  const float* qbase = q + ((size_t)(b * NN + nc * 64) * DD + h * DH);
  for (int f = tid; f < 1024; f += 256) {
    int row = f >> 4, c4 = f & 15;
    *(float4*)&Qs[row][c4 * 4] = *(const float4*)(qbase + (size_t)row * DD + c4 * 4);
  }
  int nl = tid >> 3, m = tid & 7;
  for (int r = 0; r < RR; ++r) {
    const float* pbase = proj + (size_t)(r * HH + h) * DH * MM;
    for (int f = tid; f < DH * MM / 4; f += 256)
      ((float4*)Ps)[f] = ((const float4*)pbase)[f];
    __syncthreads();
    float s0 = 0.f, s1 = 0.f;
#pragma unroll
    for (int kk = 0; kk < DH; ++kk) {
      float p = Ps[kk][m];
      s0 += Qs[nl][kk] * p;
      s1 += Qs[nl + 32][kk] * p;
    }
    Ss[nl][m] = s0;
    Ss[nl + 32][m] = s1;
    __syncthreads();
    if (tid < 64) {
      float best = Ss[tid][0];
      int bm = 0;
#pragma unroll
      for (int mm = 1; mm < MM; ++mm) {
        float vv = Ss[tid][mm];
        if (vv > best) { best = vv; bm = mm; }  // first-max tie-break (jnp.argmax)
      }
      codes[(size_t)((b * RR + r) * HH + h) * NN + nc * 64 + tid] = bm;
    }
    __syncthreads();
  }
}

// ---------------------------------------------------------------------------
// Kernel 2: stable counting sort via packed-u64 wave scan.
// Valence scaling is a positive-integer monotone map -> argsort invariant.
// ---------------------------------------------------------------------------
__global__ __launch_bounds__(256) void k_sort(const int* __restrict__ codes,
                                              int* __restrict__ idxo) {
  int gblk = blockIdx.x;
  const int* cg = codes + (size_t)gblk * NN;
  int* ig = idxo + (size_t)gblk * NN;
  int tid = threadIdx.x, lane = tid & 63, w = tid >> 6;
  __shared__ u64 wtot[4][2];
  int myc[16];
#pragma unroll
  for (int qd = 0; qd < 4; ++qd) {
    int4 t4 = ((const int4*)(cg + tid * 16))[qd];
    myc[qd * 4 + 0] = t4.x; myc[qd * 4 + 1] = t4.y;
    myc[qd * 4 + 2] = t4.z; myc[qd * 4 + 3] = t4.w;
  }
  u64 c01 = 0, c23 = 0;
#pragma unroll
  for (int i = 0; i < 16; ++i) {
    int k = myc[i];
    u64 one = 1ull << (16 * (k & 3));
    if (k < 4) c01 += one; else c23 += one;
  }
  u64 i01 = c01, i23 = c23;
#pragma unroll
  for (int d = 1; d < 64; d <<= 1) {
    u64 t0 = __shfl_up(i01, d);
    u64 t1 = __shfl_up(i23, d);
    if (lane >= d) { i01 += t0; i23 += t1; }
  }
  if (lane == 63) { wtot[w][0] = i01; wtot[w][1] = i23; }
  __syncthreads();
  u64 base01 = 0, base23 = 0, g01 = 0, g23 = 0;
#pragma unroll
  for (int ww = 0; ww < 4; ++ww) {
    u64 a = wtot[ww][0], bq = wtot[ww][1];
    if (ww < w) { base01 += a; base23 += bq; }
    g01 += a; g23 += bq;
  }
  u64 p01 = g01 + (g01 << 16); p01 += (p01 << 32);
  u64 p23 = g23 + (g23 << 16); p23 += (p23 << 32);
  u64 cb01 = p01 << 16;
  u64 tot01 = (p01 >> 48) & 0xffffull;
  u64 cb23 = (p23 << 16) + tot01 * 0x0001000100010001ull;
  u64 o01 = cb01 + base01 + (i01 - c01);
  u64 o23 = cb23 + base23 + (i23 - c23);
#pragma unroll
  for (int i = 0; i < 16; ++i) {
    int k = myc[i];
    int sh = 16 * (k & 3);
    int off;
    if (k < 4) { off = (int)((o01 >> sh) & 0xffffull); o01 += 1ull << sh; }
    else       { off = (int)((o23 >> sh) & 0xffffull); o23 += 1ull << sh; }
    ig[off] = tid * 16 + i;
  }
}

// ---------------------------------------------------------------------------
// per-bucket output writeback (once per c, 32 scalar stores per lane)
// ---------------------------------------------------------------------------
__device__ __forceinline__ void write_c(const f32x4* acc_o, const float attA[4][4],
                                        int b, int h, int cblk, int w, int g, int cl,
                                        float* __restrict__ out,
                                        float* __restrict__ attn_part,
                                        float* __restrict__ attn_out, int atomic_attn) {
#pragma unroll
  for (int i = 0; i < 4; ++i) {
    int srow = 16 * w + 4 * g + i;
    size_t obase = (size_t)(b * NN + cblk * 64 + srow) * DD + h * DH;
#pragma unroll
    for (int t = 0; t < 4; ++t)
      out[obase + 16 * t + cl] = acc_o[t][i] * 0.25f;
  }
  if (atomic_attn) {
    const float sc = 1.f / (RR * HH);
#pragma unroll
    for (int i = 0; i < 4; ++i) {
      int srow = 16 * w + 4 * g + i;
#pragma unroll
      for (int t = 0; t < 4; ++t)
        atomicAdd(attn_out + (((size_t)b * CC + cblk) * 64 + srow) * 64 + 16 * t + cl,
                  attA[t][i] * sc);
    }
  } else {
#pragma unroll
    for (int i = 0; i < 4; ++i) {
      int srow = 16 * w + 4 * g + i;
#pragma unroll
      for (int t = 0; t < 4; ++t)
        attn_part[(((size_t)(b * HH + h) * CC + cblk) * 64 + srow) * 64 + 16 * t + cl] =
            attA[t][i];
    }
  }
}

// ---------------------------------------------------------------------------
// Kernel 3: bucketed attention. Block = (b,h,4 buckets), grid 512 (2/CU).
// Outer loop cq (NOT unrolled; qh[2] statically indexed), inner loop r (fully
// unrolled; KL/VT parity = r&1 is compile-time). Both KL (K f32, DMA dest)
// and VTl (V^T bf16) double-buffered -> ONE __syncthreads per (cq,r) tile.
// Per tile: issue V(next) loads + K(next) DMA at top; compute QK/softmax/PV;
// pack V(next) (compiler auto-emits counted vmcnt leaving K-DMAs in flight);
// barrier (vmcnt(0) drains K-DMA issued a full compute phase earlier).
// V-prefetch uses a CONTIGUOUS float4[4] (r6/r7 NaN was UB reading past
// separate float4 locals). Q for bucket cq+1: raw loads at r==1, convert at
// bucket end (deferred-convert keeps vmcnt waits late).
// ---------------------------------------------------------------------------
__global__ __launch_bounds__(256, 2) void k_attn(const float* __restrict__ q,
                                                 const float* __restrict__ kmat,
                                                 const float* __restrict__ vmat,
                                                 const int* __restrict__ idxs,
                                                 float* __restrict__ out,
                                                 float* __restrict__ attn_part,
                                                 float* __restrict__ attn_out,
                                                 int atomic_attn) {
  __shared__ __align__(16) char KL[2][16384];   // K f32 double buffer (DMA dest)
  __shared__ __align__(16) char VTl[2][8192];   // V^T bf16 double buffer
  __shared__ __align__(16) char Plds[8192];     // P bf16, wave-private rows
  __shared__ int sidxL[RR][CG * 64];

  // XCD swizzle: 512 blocks, 8 XCDs, 64 consecutive slots each
  int bid = blockIdx.x;
  int blk = (bid & 7) * 64 + (bid >> 3);
  int cgi = blk & 15;
  int h = (blk >> 4) & 15;
  int b = blk >> 8;
  int cbase = cgi * CG;

  int tid = threadIdx.x;
  int lane = tid & 63;
  int w = tid >> 6;
  int g = lane >> 4;
  int cl = lane & 15;
  int cl2 = lane & 15, sub = lane >> 4;  // K-DMA roles
  int e2 = tid & 31, dg = tid >> 5;      // V staging roles

  // ---- sidx for all (r, c in group): 4 coalesced loads/thread ----
#pragma unroll
  for (int k = 0; k < RR; ++k)
    sidxL[k][tid] = idxs[(size_t)((b * RR + k) * HH + h) * NN + cbase * 64 + tid];

  const char* kbase = (const char*)(kmat + (size_t)b * NN * DD + h * DH);
  const float* vbase = vmat + (size_t)b * NN * DD + h * DH;
  const float* qrow0 = q + (size_t)(b * NN + cbase * 64 + 16 * w + cl) * DD + h * DH;

  // ---- Q raw loads for bucket 0 (issued before first barrier) ----
  float4 qraw[4];
#pragma unroll
  for (int ks = 0; ks < 2; ++ks) {
    qraw[2 * ks] = *(const float4*)(qrow0 + 32 * ks + 8 * g);
    qraw[2 * ks + 1] = *(const float4*)(qrow0 + 32 * ks + 8 * g + 4);
  }
  __syncthreads();  // sidx visible

  // ---- prologue: V(0) load+pack -> VTl[0], K(0) DMA -> KL[0] ----
  {
    const int* s0 = &sidxL[0][0];
    const float* v0 = vbase + (size_t)s0[2 * e2] * DD + 8 * dg;
    const float* v1 = vbase + (size_t)s0[2 * e2 + 1] * DD + 8 * dg;
    float4 vt4[4];
    vt4[0] = *(const float4*)v0; vt4[1] = *(const float4*)(v0 + 4);
    vt4[2] = *(const float4*)v1; vt4[3] = *(const float4*)(v1 + 4);
    int row = s0[16 * w + cl2];
    const char* gsrc = kbase + (size_t)row * 4096 + sub * 16;
#pragma unroll
    for (int qq = 0; qq < 4; ++qq)
      load_lds16(gsrc + qq * 64, KL[0] + w * 4096 + qq * 1024);
    const float* r0 = (const float*)&vt4[0];
    const float* r1 = (const float*)&vt4[2];
#pragma unroll
    for (int j = 0; j < 8; ++j) {
      unsigned pk = (unsigned)f2bf(r0[j]) | ((unsigned)f2bf(r1[j]) << 16);
      *(unsigned*)(VTl[0] + swz(8 * dg + j, 4 * e2)) = pk;
    }
  }
  __syncthreads();  // drains K(0) DMA; V(0) pack visible

  // ---- convert Q for bucket 0 ----
  bf16x8 qh[2];
#pragma unroll
  for (int ks = 0; ks < 2; ++ks)
    qh[ks] = pack8(qraw[2 * ks], qraw[2 * ks + 1], 0.125f);

  f32x4 acc_o[4];
  float attA[4][4];
#pragma unroll
  for (int t = 0; t < 4; ++t) {
    acc_o[t] = (f32x4){0.f, 0.f, 0.f, 0.f};
#pragma unroll
    for (int i = 0; i < 4; ++i) attA[t][i] = 0.f;
  }

#pragma unroll 1
  for (int cq = 0; cq < CG; ++cq) {
#pragma unroll
    for (int r = 0; r < RR; ++r) {
      const char* KLcur = KL[r & 1];
      const char* VTcur = VTl[r & 1];
      const bool has_next = (r < RR - 1) || (cq < CG - 1);

      // ---- B: prefetch next tile: V loads (4) then K DMA (4, newest) ----
      float4 vt4[4];  // CONTIGUOUS array (the r6/r7 UB fix)
      if (has_next) {
        const int* sn = (r < RR - 1) ? &sidxL[r + 1][cq * 64]
                                     : &sidxL[0][(cq + 1) * 64];
        const float* v0 = vbase + (size_t)sn[2 * e2] * DD + 8 * dg;
        const float* v1 = vbase + (size_t)sn[2 * e2 + 1] * DD + 8 * dg;
        vt4[0] = *(const float4*)v0; vt4[1] = *(const float4*)(v0 + 4);
        vt4[2] = *(const float4*)v1; vt4[3] = *(const float4*)(v1 + 4);
        int row = sn[16 * w + cl2];
        const char* gsrc = kbase + (size_t)row * 4096 + sub * 16;
#pragma unroll
        for (int qq = 0; qq < 4; ++qq)
          load_lds16(gsrc + qq * 64, KL[(r + 1) & 1] + w * 4096 + qq * 1024);
      }
      // ---- Q raw prefetch for next bucket (deferred convert) ----
      if (r == 1 && cq < CG - 1) {
        const float* qrn = qrow0 + (size_t)(cq + 1) * 64 * DD;
#pragma unroll
        for (int ks = 0; ks < 2; ++ks) {
          qraw[2 * ks] = *(const float4*)(qrn + 32 * ks + 8 * g);
          qraw[2 * ks + 1] = *(const float4*)(qrn + 32 * ks + 8 * g + 4);
        }
      }

      // ---- C: QK^T from f32 K-LDS (ds_read_b128 x2 + v_perm truncation) ----
      f32x4 s4[4];
#pragma unroll
      for (int t = 0; t < 4; ++t) s4[t] = (f32x4){0.f, 0.f, 0.f, 0.f};
      __builtin_amdgcn_s_setprio(1);
#pragma unroll
      for (int t = 0; t < 4; ++t) {
#pragma unroll
        for (int ks = 0; ks < 2; ++ks) {
          int base = t * 4096 + (2 * ks + (g >> 1)) * 1024 + (g & 1) * 512 + cl * 16;
          f32x4 f0 = *(const f32x4*)(KLcur + base);
          f32x4 f1 = *(const f32x4*)(KLcur + base + 256);
          const unsigned* u0 = (const unsigned*)&f0;
          const unsigned* u1 = (const unsigned*)&f1;
          union { bf16x8 v; unsigned u[4]; } kb;
          kb.u[0] = __builtin_amdgcn_perm(u0[1], u0[0], 0x07060302);
          kb.u[1] = __builtin_amdgcn_perm(u0[3], u0[2], 0x07060302);
          kb.u[2] = __builtin_amdgcn_perm(u1[1], u1[0], 0x07060302);
          kb.u[3] = __builtin_amdgcn_perm(u1[3], u1[2], 0x07060302);
          s4[t] = __builtin_amdgcn_mfma_f32_16x16x32_bf16(qh[ks], kb.v, s4[t], 0, 0, 0);
        }
      }
      __builtin_amdgcn_s_setprio(0);

      // ---- D: softmax (row 16w+4g+i spans the 16 lanes of group g) ----
#pragma unroll
      for (int i = 0; i < 4; ++i) {
        float mx = fmaxf(fmaxf(s4[0][i], s4[1][i]), fmaxf(s4[2][i], s4[3][i]));
        mx = fmaxf(mx, __shfl_xor(mx, 1));
        mx = fmaxf(mx, __shfl_xor(mx, 2));
        mx = fmaxf(mx, __shfl_xor(mx, 4));
        mx = fmaxf(mx, __shfl_xor(mx, 8));
        float sm = 0.f;
#pragma unroll
        for (int t = 0; t < 4; ++t) {
          float e = __expf(s4[t][i] - mx);
          s4[t][i] = e;
          sm += e;
        }
        sm += __shfl_xor(sm, 1);
        sm += __shfl_xor(sm, 2);
        sm += __shfl_xor(sm, 4);
        sm += __shfl_xor(sm, 8);
        float inv = __builtin_amdgcn_rcpf(sm);
#pragma unroll
        for (int t = 0; t < 4; ++t) {
          s4[t][i] *= inv;
          attA[t][i] += s4[t][i];
        }
      }

      // ---- E: P -> wave-private LDS (in-order within wave, no barrier) ----
#pragma unroll
      for (int i = 0; i < 4; ++i) {
        int srow = 16 * w + 4 * g + i;
#pragma unroll
        for (int t = 0; t < 4; ++t)
          *(unsigned short*)(Plds + swz(srow, 2 * (16 * t + cl))) = f2bf(s4[t][i]);
      }
      bf16x8 pa[2];
#pragma unroll
      for (int ks = 0; ks < 2; ++ks)
        pa[ks] = *(const bf16x8*)(Plds + swz(16 * w + cl, ks * 64 + g * 16));

      // ---- F: PV (reads VTcur) ----
      __builtin_amdgcn_s_setprio(1);
#pragma unroll
      for (int t = 0; t < 4; ++t)
#pragma unroll
        for (int ks = 0; ks < 2; ++ks) {
          bf16x8 vt = *(const bf16x8*)(VTcur + swz(16 * t + cl, ks * 64 + g * 16));
          acc_o[t] = __builtin_amdgcn_mfma_f32_16x16x32_bf16(pa[ks], vt, acc_o[t], 0, 0, 0);
        }
      __builtin_amdgcn_s_setprio(0);

      // ---- G: pack V(next) into the OTHER VT buffer; single per-tile barrier ----
      if (has_next) {
        const float* r0 = (const float*)&vt4[0];
        const float* r1 = (const float*)&vt4[2];
#pragma unroll
        for (int j = 0; j < 8; ++j) {
          unsigned pk = (unsigned)f2bf(r0[j]) | ((unsigned)f2bf(r1[j]) << 16);
          *(unsigned*)(VTl[(r + 1) & 1] + swz(8 * dg + j, 4 * e2)) = pk;
        }
        __syncthreads();  // drains K-DMA (issued a full compute phase ago)
      }
    }

    // ---- bucket epilogue: write out, reset acc, convert next bucket's Q ----
    write_c(acc_o, attA, b, h, cbase + cq, w, g, cl, out, attn_part, attn_out,
            atomic_attn);
    if (cq < CG - 1) {
#pragma unroll
      for (int t = 0; t < 4; ++t) {
        acc_o[t] = (f32x4){0.f, 0.f, 0.f, 0.f};
#pragma unroll
        for (int i = 0; i < 4; ++i) attA[t][i] = 0.f;
      }
#pragma unroll
      for (int ks = 0; ks < 2; ++ks)
        qh[ks] = pack8(qraw[2 * ks], qraw[2 * ks + 1], 0.125f);
    }
  }
}

// ---------------------------------------------------------------------------
// Kernel 4: attn_out = (1/(R*H)) * sum_h attn_part
// ---------------------------------------------------------------------------
__global__ __launch_bounds__(256) void k_attn_reduce(const float* __restrict__ part,
                                                     float* __restrict__ attn_out) {
  size_t o = (size_t)blockIdx.x * 256 + threadIdx.x;
  int se = (int)(o & 4095);
  size_t bc = o >> 12;
  int c = (int)(bc & (CC - 1));
  int b = (int)(bc >> 6);
  float s = 0.f;
  const float* p = part + ((size_t)b * HH * CC + c) * 4096 + se;
#pragma unroll
  for (int h = 0; h < HH; ++h) s += p[(size_t)h * CC * 4096];
  attn_out[o] = s * (1.f / (RR * HH));
}

extern "C" void kernel_launch(void* const* d_in, const int* in_sizes, int n_in,
                              void* d_out, int out_size, void* d_ws, size_t ws_size,
                              hipStream_t stream) {
  const float* q = (const float*)d_in[0];
  const float* k = (const float*)d_in[1];
  const float* v = (const float*)d_in[2];
  // d_in[3] (valence), d_in[5] (valence_scale): positive-int monotone code scale
  // -> argsort order invariant -> dead inputs.
  const float* proj = (const float*)d_in[4];
  float* out = (float*)d_out;
  float* attn_out = out + (size_t)BB * NN * DD;

  int* codes = (int*)d_ws;
  int* idxs = codes + (size_t)BB * RR * HH * NN;
  float* attn_part = (float*)(idxs + (size_t)BB * RR * HH * NN);
  size_t need = (size_t)BB * RR * HH * NN * 8 + (size_t)BB * HH * CC * 4096 * 4;
  int atomic_attn = (ws_size < need) ? 1 : 0;
  if (atomic_attn)
    hipMemsetAsync(attn_out, 0, (size_t)BB * CC * 4096 * sizeof(float), stream);

  k_hash<<<BB * HH * CC, 256, 0, stream>>>(q, proj, codes);
  k_sort<<<BB * RR * HH, 256, 0, stream>>>(codes, idxs);
  k_attn<<<BB * HH * (CC / CG), 256, 0, stream>>>(q, k, v, idxs, out, attn_part,
                                                  attn_out, atomic_attn);
  if (!atomic_attn)
    k_attn_reduce<<<BB * CC * 4096 / 256, 256, 0, stream>>>(attn_part, attn_out);
}

// Round 9
// 90.698 us; speedup vs baseline: 1.0885x; 1.0885x over previous
//
#include <hip/hip_runtime.h>
#include <hip/hip_bf16.h>

#define BB 2
#define NN 4096
#define DD 1024
#define HH 16
#define RR 4
#define MM 8
#define CC 64
#define DH 64
#define PAD 68

typedef __attribute__((ext_vector_type(8))) short bf16x8;
typedef __attribute__((ext_vector_type(8))) unsigned short ushort8;
typedef __attribute__((ext_vector_type(4))) float f32x4;
typedef unsigned long long u64;

__device__ __forceinline__ unsigned short f2bf(float x) {  // RNE via HW cvt
  union { __hip_bfloat16 b; unsigned short u; } cv;
  cv.b = __float2bfloat16(x);
  return cv.u;
}
// swizzled byte address in a [64 rows][128 bytes] LDS tile (conflict-free b128)
__device__ __forceinline__ int swz(int row, int colbyte) {
  return row * 128 + (colbyte ^ ((row & 7) << 4));
}
__device__ __forceinline__ bf16x8 pack8(float4 a, float4 b, float sc) {
  bf16x8 r;
  const float* pa = (const float*)&a;
  const float* pb = (const float*)&b;
#pragma unroll
  for (int j = 0; j < 4; ++j) {
    r[j] = (short)f2bf(pa[j] * sc);
    r[j + 4] = (short)f2bf(pb[j] * sc);
  }
  return r;
}
// async global->LDS, 16B per lane; LDS dest = base + lane*16 (wave-uniform base)
__device__ __forceinline__ void load_lds16(const void* g, void* l) {
  __builtin_amdgcn_global_load_lds(
      (const __attribute__((address_space(1))) unsigned*)g,
      (__attribute__((address_space(3))) unsigned*)l, 16, 0, 0);
}

// ---------------------------------------------------------------------------
// Kernel 0: K/V -> bf16 head-major panels kbf/vbf[b][h][n][64].
// Streaming: coalesced 4KB row reads, 128B-chunk writes. ~96 MB traffic.
// ---------------------------------------------------------------------------
__global__ __launch_bounds__(256) void k_cvt(const float* __restrict__ kmat,
                                             const float* __restrict__ vmat,
                                             unsigned short* __restrict__ kbf,
                                             unsigned short* __restrict__ vbf) {
  int bid = blockIdx.x;            // BB * (NN/16) = 512
  int b = bid >> 8;
  int n0 = (bid & 255) * 16;
  int tid = threadIdx.x;
  int h = tid >> 4, d4 = tid & 15;
#pragma unroll 4
  for (int it = 0; it < 16; ++it) {
    int row = n0 + it;
    size_t src = (size_t)(b * NN + row) * DD + tid * 4;
    float4 kv = *(const float4*)(kmat + src);
    float4 vv = *(const float4*)(vmat + src);
    size_t dst = ((size_t)(b * HH + h) * NN + row) * 64 + d4 * 4;
    const float* kf = (const float*)&kv;
    const float* vf = (const float*)&vv;
    u64 kp = (u64)f2bf(kf[0]) | ((u64)f2bf(kf[1]) << 16) |
             ((u64)f2bf(kf[2]) << 32) | ((u64)f2bf(kf[3]) << 48);
    u64 vp = (u64)f2bf(vf[0]) | ((u64)f2bf(vf[1]) << 16) |
             ((u64)f2bf(vf[2]) << 32) | ((u64)f2bf(vf[3]) << 48);
    *(u64*)(kbf + dst) = kp;
    *(u64*)(vbf + dst) = vp;
  }
}

// ---------------------------------------------------------------------------
// Kernel 1: LSH hash codes (f32 exact -> bucketing identical to reference)
// ---------------------------------------------------------------------------
__global__ __launch_bounds__(256) void k_hash(const float* __restrict__ q,
                                              const float* __restrict__ proj,
                                              int* __restrict__ codes) {
  int blk = blockIdx.x;
  int nc = blk & (CC - 1);
  int h = (blk >> 6) & (HH - 1);
  int b = blk >> 10;
  __shared__ float Qs[64][PAD];
  __shared__ float Ps[DH][MM];
  __shared__ float Ss[64][9];
  int tid = threadIdx.x;
  const float* qbase = q + ((size_t)(b * NN + nc * 64) * DD + h * DH);
  for (int f = tid; f < 1024; f += 256) {
    int row = f >> 4, c4 = f & 15;
    *(float4*)&Qs[row][c4 * 4] = *(const float4*)(qbase + (size_t)row * DD + c4 * 4);
  }
  int nl = tid >> 3, m = tid & 7;
  for (int r = 0; r < RR; ++r) {
    const float* pbase = proj + (size_t)(r * HH + h) * DH * MM;
    for (int f = tid; f < DH * MM / 4; f += 256)
      ((float4*)Ps)[f] = ((const float4*)pbase)[f];
    __syncthreads();
    float s0 = 0.f, s1 = 0.f;
#pragma unroll
    for (int kk = 0; kk < DH; ++kk) {
      float p = Ps[kk][m];
      s0 += Qs[nl][kk] * p;
      s1 += Qs[nl + 32][kk] * p;
    }
    Ss[nl][m] = s0;
    Ss[nl + 32][m] = s1;
    __syncthreads();
    if (tid < 64) {
      float best = Ss[tid][0];
      int bm = 0;
#pragma unroll
      for (int mm = 1; mm < MM; ++mm) {
        float vv = Ss[tid][mm];
        if (vv > best) { best = vv; bm = mm; }  // first-max tie-break (jnp.argmax)
      }
      codes[(size_t)((b * RR + r) * HH + h) * NN + nc * 64 + tid] = bm;
    }
    __syncthreads();
  }
}

// ---------------------------------------------------------------------------
// Kernel 2: stable counting sort via packed-u64 wave scan.
// Valence scaling is a positive-integer monotone map -> argsort invariant.
// ---------------------------------------------------------------------------
__global__ __launch_bounds__(256) void k_sort(const int* __restrict__ codes,
                                              int* __restrict__ idxo) {
  int gblk = blockIdx.x;
  const int* cg = codes + (size_t)gblk * NN;
  int* ig = idxo + (size_t)gblk * NN;
  int tid = threadIdx.x, lane = tid & 63, w = tid >> 6;
  __shared__ u64 wtot[4][2];
  int myc[16];
#pragma unroll
  for (int qd = 0; qd < 4; ++qd) {
    int4 t4 = ((const int4*)(cg + tid * 16))[qd];
    myc[qd * 4 + 0] = t4.x; myc[qd * 4 + 1] = t4.y;
    myc[qd * 4 + 2] = t4.z; myc[qd * 4 + 3] = t4.w;
  }
  u64 c01 = 0, c23 = 0;
#pragma unroll
  for (int i = 0; i < 16; ++i) {
    int k = myc[i];
    u64 one = 1ull << (16 * (k & 3));
    if (k < 4) c01 += one; else c23 += one;
  }
  u64 i01 = c01, i23 = c23;
#pragma unroll
  for (int d = 1; d < 64; d <<= 1) {
    u64 t0 = __shfl_up(i01, d);
    u64 t1 = __shfl_up(i23, d);
    if (lane >= d) { i01 += t0; i23 += t1; }
  }
  if (lane == 63) { wtot[w][0] = i01; wtot[w][1] = i23; }
  __syncthreads();
  u64 base01 = 0, base23 = 0, g01 = 0, g23 = 0;
#pragma unroll
  for (int ww = 0; ww < 4; ++ww) {
    u64 a = wtot[ww][0], bq = wtot[ww][1];
    if (ww < w) { base01 += a; base23 += bq; }
    g01 += a; g23 += bq;
  }
  u64 p01 = g01 + (g01 << 16); p01 += (p01 << 32);
  u64 p23 = g23 + (g23 << 16); p23 += (p23 << 32);
  u64 cb01 = p01 << 16;
  u64 tot01 = (p01 >> 48) & 0xffffull;
  u64 cb23 = (p23 << 16) + tot01 * 0x0001000100010001ull;
  u64 o01 = cb01 + base01 + (i01 - c01);
  u64 o23 = cb23 + base23 + (i23 - c23);
#pragma unroll
  for (int i = 0; i < 16; ++i) {
    int k = myc[i];
    int sh = 16 * (k & 3);
    int off;
    if (k < 4) { off = (int)((o01 >> sh) & 0xffffull); o01 += 1ull << sh; }
    else       { off = (int)((o23 >> sh) & 0xffffull); o23 += 1ull << sh; }
    ig[off] = tid * 16 + i;
  }
}

// ---------------------------------------------------------------------------
// Kernel 3: bucketed attention. Block=(b,h,c), 4 waves, 4 r-iters.
// LDS 33KB -> 4 blocks/CU: KB dbuf 16K (bf16 K, global_load_lds dest) +
// VT 8K + PL 8K + sidx 1K. K-DMA issued at iter TOP into other buffer ->
// drained at bottom barrier (distance = full compute phase). Standard
// __syncthreads only (2/iter).
// SWAPPED QK^T: S^T = mfma(A=K, B=Q) -> C[row=e_local][col=s_local]; softmax
// over e is in-lane over 16 regs + 2 shfl_xor (g bits). PV: O^T = mfma(A=V^T,
// B=P). Fragment lane-maps for K/Q/V identical to the unswapped version.
// KB layout (from DMA dest=base+lane*16): elem(row 16w+cl2, colbyte qq*64+
// sub*16) at w*2048 + qq*1024 + sub*256 + cl2*16; frag read = contiguous
// 1KB/instr -> conflict-free.
// ---------------------------------------------------------------------------
__global__ __launch_bounds__(256, 4) void k_attn(const float* __restrict__ q,
                                                 const unsigned short* __restrict__ kbf,
                                                 const unsigned short* __restrict__ vbf,
                                                 const int* __restrict__ idxs,
                                                 float* __restrict__ out,
                                                 float* __restrict__ attn_part,
                                                 float* __restrict__ attn_out,
                                                 int atomic_attn) {
  __shared__ __align__(16) char KB[2][8192];  // K bf16 double buffer (DMA dest)
  __shared__ __align__(16) char VT[8192];     // V^T bf16, swizzled
  __shared__ __align__(16) char PL[8192];     // P bf16 [s][e], wave-private 2K rows
  __shared__ int sidx[RR][64];

  // XCD-aware bijective swizzle: 2048 blocks, 8 XCDs, chunk 256
  int bid = blockIdx.x;
  int blk = (bid & 7) * 256 + (bid >> 3);
  int cblk = blk & 63;
  int h = (blk >> 6) & 15;
  int b = blk >> 10;
  int tid = threadIdx.x;
  int lane = tid & 63;
  int w = tid >> 6;
  int g = lane >> 4;
  int cl = lane & 15;
  int e2 = tid & 31, dg = (tid >> 5) & 7;  // V staging roles

  sidx[tid >> 6][tid & 63] =
      idxs[(size_t)((b * RR + (tid >> 6)) * HH + h) * NN + cblk * 64 + (tid & 63)];

  const char* kp = (const char*)(kbf + (size_t)(b * HH + h) * NN * 64);
  const unsigned short* vp = vbf + (size_t)(b * HH + h) * NN * 64;

  // ---- Q fragments (B-operand; lane map identical to A) pre-scaled by 1/8 ----
  const float* qrow = q + (size_t)(b * NN + cblk * 64 + 16 * w + cl) * DD + h * DH;
  bf16x8 qh[2];
#pragma unroll
  for (int ks = 0; ks < 2; ++ks)
    qh[ks] = pack8(*(const float4*)(qrow + 32 * ks + 8 * g),
                   *(const float4*)(qrow + 32 * ks + 8 * g + 4), 0.125f);

  __syncthreads();  // sidx visible

  // ---- prologue: K(0) DMA, V(0) load+pack ----
  {
    int row = sidx[0][16 * w + cl];
    const char* gs = kp + (size_t)row * 128 + g * 16;
    load_lds16(gs, KB[0] + w * 2048);
    load_lds16(gs + 64, KB[0] + w * 2048 + 1024);
    ushort8 v0r = *(const ushort8*)(vp + (size_t)sidx[0][2 * e2] * 64 + dg * 8);
    ushort8 v1r = *(const ushort8*)(vp + (size_t)sidx[0][2 * e2 + 1] * 64 + dg * 8);
#pragma unroll
    for (int j = 0; j < 8; ++j) {
      unsigned pk = (unsigned)(unsigned short)v0r[j] |
                    ((unsigned)(unsigned short)v1r[j] << 16);
      *(unsigned*)(VT + swz(8 * dg + j, 4 * e2)) = pk;
    }
  }
  __syncthreads();  // K(0) drained, VT(0) visible

  f32x4 acc_o[4];
  float attA[4][4];
#pragma unroll
  for (int t = 0; t < 4; ++t) {
    acc_o[t] = (f32x4){0.f, 0.f, 0.f, 0.f};
#pragma unroll
    for (int i = 0; i < 4; ++i) attA[t][i] = 0.f;
  }

#pragma unroll
  for (int r = 0; r < RR; ++r) {
    // ---- prefetch (r+1): K DMA into other buffer + V reg loads (at TOP) ----
    ushort8 n0r, n1r;
    if (r < RR - 1) {
      int row = sidx[r + 1][16 * w + cl];
      const char* gs = kp + (size_t)row * 128 + g * 16;
      load_lds16(gs, KB[(r + 1) & 1] + w * 2048);
      load_lds16(gs + 64, KB[(r + 1) & 1] + w * 2048 + 1024);
      n0r = *(const ushort8*)(vp + (size_t)sidx[r + 1][2 * e2] * 64 + dg * 8);
      n1r = *(const ushort8*)(vp + (size_t)sidx[r + 1][2 * e2 + 1] * 64 + dg * 8);
    }

    // ---- QK^T swapped: S^T[e][s], C: e_local=4g+i (tile t), s=cl ----
    f32x4 s4[4];
#pragma unroll
    for (int t = 0; t < 4; ++t) s4[t] = (f32x4){0.f, 0.f, 0.f, 0.f};
    __builtin_amdgcn_s_setprio(1);
#pragma unroll
    for (int t = 0; t < 4; ++t)
#pragma unroll
      for (int ks = 0; ks < 2; ++ks) {
        bf16x8 kf = *(const bf16x8*)(KB[r & 1] + t * 2048 + ks * 1024 + g * 256 + cl * 16);
        s4[t] = __builtin_amdgcn_mfma_f32_16x16x32_bf16(kf, qh[ks], s4[t], 0, 0, 0);
      }
    __builtin_amdgcn_s_setprio(0);

    // ---- softmax over e: in-lane tree over 16 regs + 2 shfl over g-lanes ----
    {
      f32x4 m4 = s4[0];
#pragma unroll
      for (int t = 1; t < 4; ++t)
#pragma unroll
        for (int i = 0; i < 4; ++i) m4[i] = fmaxf(m4[i], s4[t][i]);
      float mx = fmaxf(fmaxf(m4[0], m4[1]), fmaxf(m4[2], m4[3]));
      mx = fmaxf(mx, __shfl_xor(mx, 16));
      mx = fmaxf(mx, __shfl_xor(mx, 32));
      float sm = 0.f;
#pragma unroll
      for (int t = 0; t < 4; ++t)
#pragma unroll
        for (int i = 0; i < 4; ++i) {
          float e = __expf(s4[t][i] - mx);
          s4[t][i] = e;
          sm += e;
        }
      sm += __shfl_xor(sm, 16);
      sm += __shfl_xor(sm, 32);
      float inv = __builtin_amdgcn_rcpf(sm);
#pragma unroll
      for (int t = 0; t < 4; ++t)
#pragma unroll
        for (int i = 0; i < 4; ++i) {
          s4[t][i] *= inv;
          attA[t][i] += s4[t][i];
        }
    }

    // ---- P -> PL[s=cl][e] (4x ds_write_b64; e=16t+4g+i consecutive in i) ----
#pragma unroll
    for (int t = 0; t < 4; ++t) {
      u64 pk = (u64)f2bf(s4[t][0]) | ((u64)f2bf(s4[t][1]) << 16) |
               ((u64)f2bf(s4[t][2]) << 32) | ((u64)f2bf(s4[t][3]) << 48);
      *(u64*)(PL + w * 2048 + swz(cl, 32 * t + 8 * g)) = pk;
    }
    bf16x8 pa[2];
#pragma unroll
    for (int ks = 0; ks < 2; ++ks)
      pa[ks] = *(const bf16x8*)(PL + w * 2048 + swz(cl, 64 * ks + 16 * g));

    // ---- PV swapped: O^T = mfma(A=V^T, B=P) ----
    __builtin_amdgcn_s_setprio(1);
#pragma unroll
    for (int t = 0; t < 4; ++t)
#pragma unroll
      for (int ks = 0; ks < 2; ++ks) {
        bf16x8 vt = *(const bf16x8*)(VT + swz(16 * t + cl, ks * 64 + g * 16));
        acc_o[t] = __builtin_amdgcn_mfma_f32_16x16x32_bf16(vt, pa[ks], acc_o[t], 0, 0, 0);
      }
    __builtin_amdgcn_s_setprio(0);

    if (r < RR - 1) {
      __syncthreads();  // VT readers done; drains K(r+1) DMA + V loads
                        // (issued a full compute phase ago)
#pragma unroll
      for (int j = 0; j < 8; ++j) {
        unsigned pk = (unsigned)(unsigned short)n0r[j] |
                      ((unsigned)(unsigned short)n1r[j] << 16);
        *(unsigned*)(VT + swz(8 * dg + j, 4 * e2)) = pk;
      }
      __syncthreads();  // VT(r+1) visible; KB[(r+1)&1] already drained
    }
  }

  // ---- epilogue: O^T layout -> lane (g,cl) holds d=16t+4g+i for s=16w+cl ----
  int srow = 16 * w + cl;
  size_t ob = (size_t)(b * NN + cblk * 64 + srow) * DD + h * DH + 4 * g;
#pragma unroll
  for (int t = 0; t < 4; ++t) {
    float4 o = make_float4(acc_o[t][0] * 0.25f, acc_o[t][1] * 0.25f,
                           acc_o[t][2] * 0.25f, acc_o[t][3] * 0.25f);
    *(float4*)(out + ob + 16 * t) = o;
  }
  size_t ab = (((size_t)(b * HH + h) * CC + cblk) * 64 + srow) * 64 + 4 * g;
  if (atomic_attn) {
    const float sc = 1.f / (RR * HH);
    size_t abase = (((size_t)b * CC + cblk) * 64 + srow) * 64 + 4 * g;
#pragma unroll
    for (int t = 0; t < 4; ++t)
#pragma unroll
      for (int i = 0; i < 4; ++i)
        atomicAdd(attn_out + abase + 16 * t + i, attA[t][i] * sc);
  } else {
#pragma unroll
    for (int t = 0; t < 4; ++t) {
      float4 o = make_float4(attA[t][0], attA[t][1], attA[t][2], attA[t][3]);
      *(float4*)(attn_part + ab + 16 * t) = o;
    }
  }
}

// ---------------------------------------------------------------------------
// Kernel 4: attn_out = (1/(R*H)) * sum_h attn_part
// ---------------------------------------------------------------------------
__global__ __launch_bounds__(256) void k_attn_reduce(const float* __restrict__ part,
                                                     float* __restrict__ attn_out) {
  size_t o = (size_t)blockIdx.x * 256 + threadIdx.x;
  int se = (int)(o & 4095);
  size_t bc = o >> 12;
  int c = (int)(bc & (CC - 1));
  int b = (int)(bc >> 6);
  float s = 0.f;
  const float* p = part + ((size_t)b * HH * CC + c) * 4096 + se;
#pragma unroll
  for (int h = 0; h < HH; ++h) s += p[(size_t)h * CC * 4096];
  attn_out[o] = s * (1.f / (RR * HH));
}

extern "C" void kernel_launch(void* const* d_in, const int* in_sizes, int n_in,
                              void* d_out, int out_size, void* d_ws, size_t ws_size,
                              hipStream_t stream) {
  const float* q = (const float*)d_in[0];
  const float* k = (const float*)d_in[1];
  const float* v = (const float*)d_in[2];
  // d_in[3] (valence), d_in[5] (valence_scale): positive-int monotone code scale
  // -> argsort order invariant -> dead inputs.
  const float* proj = (const float*)d_in[4];
  float* out = (float*)d_out;
  float* attn_out = out + (size_t)BB * NN * DD;

  const size_t n_codes = (size_t)BB * RR * HH * NN;          // 524288 ints
  const size_t n_panel = (size_t)BB * HH * NN * 64;          // 8388608 bf16
  const size_t n_part  = (size_t)BB * HH * CC * 4096;        // 8388608 f32

  int* codes = (int*)d_ws;
  int* idxs = codes + n_codes;
  unsigned short* kbf = (unsigned short*)(idxs + n_codes);
  unsigned short* vbf = kbf + n_panel;
  float* attn_part = (float*)(vbf + n_panel);

  size_t need_full = n_codes * 8 + n_panel * 4 + n_part * 4;
  int atomic_attn = (ws_size < need_full) ? 1 : 0;
  if (atomic_attn)
    hipMemsetAsync(attn_out, 0, (size_t)BB * CC * 4096 * sizeof(float), stream);

  k_cvt<<<BB * (NN / 16), 256, 0, stream>>>(k, v, kbf, vbf);
  k_hash<<<BB * HH * CC, 256, 0, stream>>>(q, proj, codes);
  k_sort<<<BB * RR * HH, 256, 0, stream>>>(codes, idxs);
  k_attn<<<BB * HH * CC, 256, 0, stream>>>(q, kbf, vbf, idxs, out, attn_part,
                                           attn_out, atomic_attn);
  if (!atomic_attn)
    k_attn_reduce<<<BB * CC * 4096 / 256, 256, 0, stream>>>(attn_part, attn_out);
}